// Round 4
// baseline (206.340 us; speedup 1.0000x reference)
//
#include <hip/hip_runtime.h>
#include <math.h>

// Tropical (max-plus) depthwise 3x3 conv, stride=1, pad=1, dil=1.
// x: (8,64,224,224) fp32; kernel: (64,1,3,3) fp32; out same shape.
// R3 design: one thread -> 4 output rows x 8 cols (2 float4). All 24 loads
// (6 rows x {2 float4 + 2 clamped halo dwords}) issued as one independent
// batch for MLP; interior strips take a fully branch-free path. NT stores
// keep the output stream from evicting input rows from L2.

#define H_DIM 224
#define W_DIM 224
#define W8 28                 // W/8 column groups (8 floats per thread)
#define STRIP 4               // output rows per thread
#define GS (H_DIM / STRIP)    // 56 strips
#define C_DIM 64
#define NEG (-INFINITY)

typedef float f4v __attribute__((ext_vector_type(4)));

__device__ __forceinline__ float m3(float a, float b, float c) {
    return fmaxf(fmaxf(a, b), c);   // -> v_max3_f32
}

__global__ __launch_bounds__(256, 2) void tropical_conv_kernel(
    const float* __restrict__ x,
    const float* __restrict__ kern,
    float* __restrict__ out,
    int total)   // total threads = B*C*GS*W8
{
    int idx = blockIdx.x * blockDim.x + threadIdx.x;
    if (idx >= total) return;

    int j8 = idx % W8;
    int t  = idx / W8;
    int g  = t % GS;
    int bc = t / GS;
    int c  = bc & (C_DIM - 1);

    const float* kc = kern + c * 9;
    float k00 = kc[0], k01 = kc[1], k02 = kc[2];
    float k10 = kc[3], k11 = kc[4], k12 = kc[5];
    float k20 = kc[6], k21 = kc[7], k22 = kc[8];

    const float* plane  = x   + (size_t)bc * (H_DIM * W_DIM);
    float*       oplane = out + (size_t)bc * (H_DIM * W_DIM);
    int j0 = j8 * 8;
    int i0 = g * STRIP;

    bool has_l = (j8 > 0);
    bool has_r = (j8 < W8 - 1);
    int  jl    = has_l ? j0 - 1 : 0;            // clamped: always in-bounds
    int  jr    = has_r ? j0 + 8 : W_DIM - 1;    // clamped: always in-bounds

    float4 v0[6], v1[6];
    float  lf[6], rg[6];

    if (g > 0 && g < GS - 1) {
        // Interior strip: rows i0-1 .. i0+4 all valid. Pure unconditional
        // load batch (24 independent loads), then 2 edge selects per row.
        const float* row = plane + (size_t)(i0 - 1) * W_DIM;
        #pragma unroll
        for (int rr = 0; rr < 6; ++rr) {
            v0[rr] = *(const float4*)(row + j0);
            v1[rr] = *(const float4*)(row + j0 + 4);
            lf[rr] = row[jl];
            rg[rr] = row[jr];
            row += W_DIM;
        }
        #pragma unroll
        for (int rr = 0; rr < 6; ++rr) {
            lf[rr] = has_l ? lf[rr] : NEG;
            rg[rr] = has_r ? rg[rr] : NEG;
        }
    } else {
        // Top/bottom strip: clamp row address, then mask out-of-range rows
        // to the tropical neutral after the (always-valid) load.
        #pragma unroll
        for (int rr = 0; rr < 6; ++rr) {
            int r  = i0 - 1 + rr;
            int rc = r < 0 ? 0 : (r >= H_DIM ? H_DIM - 1 : r);
            const float* row = plane + (size_t)rc * W_DIM;
            v0[rr] = *(const float4*)(row + j0);
            v1[rr] = *(const float4*)(row + j0 + 4);
            lf[rr] = has_l ? row[jl] : NEG;
            rg[rr] = has_r ? row[jr] : NEG;
            bool oob = (r < 0) || (r >= H_DIM);
            if (oob) {
                v0[rr] = make_float4(NEG, NEG, NEG, NEG);
                v1[rr] = make_float4(NEG, NEG, NEG, NEG);
                lf[rr] = NEG;
                rg[rr] = NEG;
            }
        }
    }

    // Expand to a 10-wide register row view: [l, v0.xyzw, v1.xyzw, r]
    float X[6][10];
    #pragma unroll
    for (int rr = 0; rr < 6; ++rr) {
        X[rr][0] = lf[rr];
        X[rr][1] = v0[rr].x; X[rr][2] = v0[rr].y;
        X[rr][3] = v0[rr].z; X[rr][4] = v0[rr].w;
        X[rr][5] = v1[rr].x; X[rr][6] = v1[rr].y;
        X[rr][7] = v1[rr].z; X[rr][8] = v1[rr].w;
        X[rr][9] = rg[rr];
    }

    #pragma unroll
    for (int o = 0; o < STRIP; ++o) {
        float ot[8];
        #pragma unroll
        for (int ci = 0; ci < 8; ++ci) {
            float m0 = m3(X[o    ][ci] + k00, X[o    ][ci + 1] + k01, X[o    ][ci + 2] + k02);
            float m1 = m3(X[o + 1][ci] + k10, X[o + 1][ci + 1] + k11, X[o + 1][ci + 2] + k12);
            float m2 = m3(X[o + 2][ci] + k20, X[o + 2][ci + 1] + k21, X[o + 2][ci + 2] + k22);
            ot[ci] = m3(m0, m1, m2);
        }
        float* orow = oplane + (size_t)(i0 + o) * W_DIM + j0;
        f4v s0 = {ot[0], ot[1], ot[2], ot[3]};
        f4v s1 = {ot[4], ot[5], ot[6], ot[7]};
        __builtin_nontemporal_store(s0, (f4v*)orow);
        __builtin_nontemporal_store(s1, (f4v*)(orow + 4));
    }
}

extern "C" void kernel_launch(void* const* d_in, const int* in_sizes, int n_in,
                              void* d_out, int out_size, void* d_ws, size_t ws_size,
                              hipStream_t stream) {
    const float* x    = (const float*)d_in[0];
    const float* kern = (const float*)d_in[1];
    float* out        = (float*)d_out;

    const int total = 8 * C_DIM * GS * W8;   // 802,816 threads
    const int block = 256;
    const int grid  = (total + block - 1) / block;
    tropical_conv_kernel<<<grid, block, 0, stream>>>(x, kern, out, total);
}

// Round 5
// 188.786 us; speedup vs baseline: 1.0930x; 1.0930x over previous
//
#include <hip/hip_runtime.h>
#include <math.h>

// Tropical (max-plus) depthwise 3x3 conv, stride=1, pad=1, dil=1.
// x: (8,64,224,224) fp32; kernel: (64,1,3,3) fp32; out same shape.
// R4 design: LDS-staged tiles via async global_load_lds (no dest VGPR ->
// compiler cannot serialize the load batch; ~16KB per block in flight).
// Block = 256 threads, tile = 16 output rows x full 224-wide row of one
// plane; input region (18 rows incl. vertical halos) is CONTIGUOUS in
// global memory -> flat coalesced 16B async copies. Compute from LDS,
// plain (cached) float4 stores -- NT stores amplified WRITE_SIZE 1.48x in R3.

#define H_DIM 224
#define W_DIM 224
#define W4 56
#define STRIP 16
#define TILES_PER_PLANE 14     // 224/16
#define C_DIM 64
#define NEG (-INFINITY)

#define LDS_ROWS 18            // STRIP + 2 halo rows
#define LDS_DW (LDS_ROWS * W_DIM)   // 4032 dwords
#define LDS_PAD 8

typedef float f4 __attribute__((ext_vector_type(4)));

typedef __attribute__((address_space(3))) void       lds_void;
typedef __attribute__((address_space(1))) const void gbl_void;

__device__ __forceinline__ void async_copy16(const float* g, float* l) {
    __builtin_amdgcn_global_load_lds((gbl_void*)g, (lds_void*)l, 16, 0, 0);
}

__device__ __forceinline__ float m3(float a, float b, float c) {
    return fmaxf(fmaxf(a, b), c);   // -> v_max3_f32
}

__global__ __launch_bounds__(256) void tropical_conv_kernel(
    const float* __restrict__ x,
    const float* __restrict__ kern,
    float* __restrict__ out)
{
    __shared__ float lds[LDS_DW + LDS_PAD];

    int b   = blockIdx.x;
    int g   = b % TILES_PER_PLANE;
    int bc  = b / TILES_PER_PLANE;
    int c   = bc & (C_DIM - 1);
    int tid = threadIdx.x;

    const float* plane  = x   + (size_t)bc * (H_DIM * W_DIM);
    float*       oplane = out + (size_t)bc * (H_DIM * W_DIM);

    // ---- async copy: input rows [g*16-1, g*16+17) -> LDS rows [0,18) ----
    // OOB rows (above row 0 / below row 223) are filled with NEG instead.
    int r0         = g * STRIP - 1;   // first input row
    int nrows      = LDS_ROWS;
    int lds_off_dw = 0;
    if (g == 0)                       { r0 = 0; nrows = 17; lds_off_dw = W_DIM; }
    else if (g == TILES_PER_PLANE - 1) { nrows = 17; }

    const float* gsrc = plane + (size_t)r0 * W_DIM;   // contiguous nrows*896 B
    int nchunk = nrows * (W_DIM / 4);                 // 16B chunks
    for (int k = tid; k < nchunk; k += 256) {
        async_copy16(gsrc + k * 4, &lds[lds_off_dw + k * 4]);
    }
    if (g == 0) {
        if (tid < W_DIM) lds[tid] = NEG;                       // row -1
    } else if (g == TILES_PER_PLANE - 1) {
        if (tid < W_DIM) lds[(LDS_ROWS - 1) * W_DIM + tid] = NEG;  // row 224
    }
    __syncthreads();   // drains vmcnt (async copies) + lgkmcnt (fills)

    // ---- taps (block-uniform -> scalar loads) ----
    const float* kc = kern + c * 9;
    float k00 = kc[0], k01 = kc[1], k02 = kc[2];
    float k10 = kc[3], k11 = kc[4], k12 = kc[5];
    float k20 = kc[6], k21 = kc[7], k22 = kc[8];

    // ---- compute: 896 output float4 per tile, 256 threads, 4 passes ----
    #pragma unroll
    for (int it = 0; it < 4; ++it) {
        int o = it * 256 + tid;
        if (o < STRIP * W4) {
            int r  = o / W4;          // 0..15 (output row within tile)
            int cc = o % W4;          // 0..55 (float4 column)
            int base = r * W_DIM + cc * 4;   // LDS dword index, row r == in row r-1
            bool hl = (cc > 0), hr = (cc < W4 - 1);
            int li = base - (hl ? 1 : 0);    // clamped left-halo index

            f4 a0 = *(const f4*)&lds[base];
            f4 a1 = *(const f4*)&lds[base + W_DIM];
            f4 a2 = *(const f4*)&lds[base + 2 * W_DIM];
            float l0 = lds[li];
            float l1 = lds[li + W_DIM];
            float l2 = lds[li + 2 * W_DIM];
            float q0 = lds[base + 4];
            float q1 = lds[base + W_DIM + 4];
            float q2 = lds[base + 2 * W_DIM + 4];
            if (!hl) { l0 = NEG; l1 = NEG; l2 = NEG; }
            if (!hr) { q0 = NEG; q1 = NEG; q2 = NEG; }

            f4 acc;
            acc.x = m3(m3(l0   + k00, a0.x + k01, a0.y + k02),
                       m3(l1   + k10, a1.x + k11, a1.y + k12),
                       m3(l2   + k20, a2.x + k21, a2.y + k22));
            acc.y = m3(m3(a0.x + k00, a0.y + k01, a0.z + k02),
                       m3(a1.x + k10, a1.y + k11, a1.z + k12),
                       m3(a2.x + k20, a2.y + k21, a2.z + k22));
            acc.z = m3(m3(a0.y + k00, a0.z + k01, a0.w + k02),
                       m3(a1.y + k10, a1.z + k11, a1.w + k12),
                       m3(a2.y + k20, a2.z + k21, a2.w + k22));
            acc.w = m3(m3(a0.z + k00, a0.w + k01, q0   + k02),
                       m3(a1.z + k10, a1.w + k11, q1   + k12),
                       m3(a2.z + k20, a2.w + k21, q2   + k22));

            *(f4*)(oplane + (size_t)(g * STRIP + r) * W_DIM + cc * 4) = acc;
        }
    }
}

extern "C" void kernel_launch(void* const* d_in, const int* in_sizes, int n_in,
                              void* d_out, int out_size, void* d_ws, size_t ws_size,
                              hipStream_t stream) {
    const float* x    = (const float*)d_in[0];
    const float* kern = (const float*)d_in[1];
    float* out        = (float*)d_out;

    const int grid = 8 * C_DIM * TILES_PER_PLANE;   // 7168 blocks
    tropical_conv_kernel<<<grid, 256, 0, stream>>>(x, kern, out);
}